// Round 7
// baseline (379.882 us; speedup 1.0000x reference)
//
#include <hip/hip_runtime.h>
#include <hip/hip_bf16.h>
#include <math.h>

#define B_  8
#define N_  1025
#define C_  512
#define H_  8
#define HD_ 64
#define M_  (B_ * N_)   // 8200
#define NCH 33          // ceil(N_/32) key chunks
#define VCS 2048        // shorts per vtc chunk: 64 dims * 32 keys
#define NROWS (64 * N_) // 65600 (bh x row)

typedef __attribute__((ext_vector_type(8))) short short8;
typedef __attribute__((ext_vector_type(4))) float f32x4;

__device__ inline unsigned short bf16u(float x) {
    __hip_bfloat16 t = __float2bfloat16(x);
    return *(unsigned short*)&t;
}
__device__ inline float bf16f(unsigned short u) {
    return __uint_as_float(((unsigned)u) << 16);
}
__device__ inline void load_lds16(const void* g, void* l) {
    __builtin_amdgcn_global_load_lds(
        (const __attribute__((address_space(1))) unsigned int*)g,
        (__attribute__((address_space(3))) unsigned int*)l, 16, 0, 0);
}

// ---------------------------------------------------------------------------
__global__ void cast_bf16_kernel(const float* __restrict__ src,
                                 unsigned short* __restrict__ dst, int n) {
    int i4 = (blockIdx.x * blockDim.x + threadIdx.x) * 4;
    if (i4 + 3 < n) {
        float4 v = *(const float4*)(src + i4);
        ushort4 p;
        p.x = bf16u(v.x); p.y = bf16u(v.y); p.z = bf16u(v.z); p.w = bf16u(v.w);
        *(ushort4*)(dst + i4) = p;
    }
}

// ---------------------------------------------------------------------------
// Geometry bias collapses to an H x 32 x 32 table (dw=dh=0; |dpx|,|dpy| only).
// ---------------------------------------------------------------------------
__global__ void bias_tab_kernel(const float* __restrict__ wg_w,
                                const float* __restrict__ wg_b,
                                float* __restrict__ tab) {
    int idx = blockIdx.x * blockDim.x + threadIdx.x;
    if (idx >= H_ * 32 * 32) return;
    int h = idx >> 10;
    int a = (idx >> 5) & 31;
    int b = idx & 31;
    float dx = logf(fmaxf((float)a * (1.0f / 33.0f), 0.001f));
    float dy = logf(fmaxf((float)b * (1.0f / 33.0f), 0.001f));
    const float* w = wg_w + h * 64;
    float acc = wg_b[h];
#pragma unroll
    for (int k = 0; k < 8; k++) {
        float f = powf(1000.0f, -(float)k * 0.125f);
        float X = 100.0f * dx * f;
        float Y = 100.0f * dy * f;
        acc += w[k]      * sinf(X);
        acc += w[8 + k]  * sinf(Y);
        acc += w[32 + k] * cosf(X);
        acc += w[40 + k] * cosf(Y);
        acc += w[48 + k] + w[56 + k];
    }
    tab[idx] = logf(fmaxf(fmaxf(acc, 0.0f), 1e-6f));
}

// ---------------------------------------------------------------------------
// MFMA GEMM, 128x128 tile, BK=32, 4 waves. QKV variant scatters q (x0.125)
// and k to [bh][tok][64]; v goes to chunk-padded transposed vtc
// [bh][chunk][dim][32].
// ---------------------------------------------------------------------------
#define GK 512

__global__ __launch_bounds__(256) void gemm_qkv_mfma(
        const unsigned short* __restrict__ A, const unsigned short* __restrict__ W,
        unsigned short* __restrict__ qb, unsigned short* __restrict__ kb,
        unsigned short* __restrict__ vtc) {
    __shared__ __align__(16) unsigned short As[128 * 32];
    __shared__ __align__(16) unsigned short Bs[128 * 32];
    int tid = threadIdx.x;
    int w = tid >> 6, lane = tid & 63;
    int quad = lane >> 4, l16 = lane & 15;
    int m0 = blockIdx.y * 128;
    int n0 = blockIdx.x * 128;
    int wr = (w >> 1) * 64, wc = (w & 1) * 64;

    int c0 = tid, c1 = tid + 256;
    int a_r0 = min(m0 + (c0 >> 2), M_ - 1), a_c0 = (c0 & 3) * 8;
    int a_r1 = min(m0 + (c1 >> 2), M_ - 1), a_c1 = (c1 & 3) * 8;
    int b_r0 = n0 + (c0 >> 2), b_r1 = n0 + (c1 >> 2);

    f32x4 acc[4][4];
    const f32x4 zero4 = {0.f, 0.f, 0.f, 0.f};
#pragma unroll
    for (int mi = 0; mi < 4; mi++)
#pragma unroll
        for (int ni = 0; ni < 4; ni++) acc[mi][ni] = zero4;

    for (int k0 = 0; k0 < GK; k0 += 32) {
        __syncthreads();
        load_lds16(A + (size_t)a_r0 * GK + k0 + a_c0, &As[w * 512]);
        load_lds16(A + (size_t)a_r1 * GK + k0 + a_c1, &As[2048 + w * 512]);
        load_lds16(W + (size_t)b_r0 * GK + k0 + a_c0, &Bs[w * 512]);
        load_lds16(W + (size_t)b_r1 * GK + k0 + a_c1, &Bs[2048 + w * 512]);
        __syncthreads();
        short8 af[4], bf[4];
#pragma unroll
        for (int mi = 0; mi < 4; mi++)
            af[mi] = *(const short8*)&As[(wr + mi * 16 + l16) * 32 + quad * 8];
#pragma unroll
        for (int ni = 0; ni < 4; ni++)
            bf[ni] = *(const short8*)&Bs[(wc + ni * 16 + l16) * 32 + quad * 8];
#pragma unroll
        for (int mi = 0; mi < 4; mi++)
#pragma unroll
            for (int ni = 0; ni < 4; ni++)
                acc[mi][ni] = __builtin_amdgcn_mfma_f32_16x16x32_bf16(
                    af[mi], bf[ni], acc[mi][ni], 0, 0, 0);
    }

    int which = n0 >> 9;                       // 0=q 1=k 2=v
    int h = ((n0 + wc) >> 6) & 7;
    if (which < 2) {
        unsigned short* dst = (which == 0) ? qb : kb;
        float sc = (which == 0) ? 0.125f : 1.0f;
#pragma unroll
        for (int mi = 0; mi < 4; mi++)
#pragma unroll
            for (int reg = 0; reg < 4; reg++) {
                int m = m0 + wr + mi * 16 + quad * 4 + reg;
                if (m < M_) {
                    int bb = m / N_;
                    int i  = m - bb * N_;
                    unsigned short* row = dst + ((size_t)(bb * H_ + h) * N_ + i) * HD_;
#pragma unroll
                    for (int ni = 0; ni < 4; ni++)
                        row[ni * 16 + l16] = bf16u(acc[mi][ni][reg] * sc);
                }
            }
    } else {
#pragma unroll
        for (int mi = 0; mi < 4; mi++)
#pragma unroll
            for (int reg = 0; reg < 4; reg++) {
                int m = m0 + wr + mi * 16 + quad * 4 + reg;
                if (m < M_) {
                    int bb = m / N_;
                    int i  = m - bb * N_;
                    int ch = i >> 5, key = i & 31;
                    size_t base = ((size_t)(bb * H_ + h) * NCH + ch) * VCS + key;
#pragma unroll
                    for (int ni = 0; ni < 4; ni++)
                        vtc[base + (size_t)(ni * 16 + l16) * 32] = bf16u(acc[mi][ni][reg]);
                }
            }
    }
}

__global__ __launch_bounds__(256) void gemm_proj_mfma(
        const unsigned short* __restrict__ A, const unsigned short* __restrict__ W,
        const float* __restrict__ bias, float* __restrict__ out) {
    __shared__ __align__(16) unsigned short As[128 * 32];
    __shared__ __align__(16) unsigned short Bs[128 * 32];
    int tid = threadIdx.x;
    int w = tid >> 6, lane = tid & 63;
    int quad = lane >> 4, l16 = lane & 15;
    int m0 = blockIdx.y * 128;
    int n0 = blockIdx.x * 128;
    int wr = (w >> 1) * 64, wc = (w & 1) * 64;

    int c0 = tid, c1 = tid + 256;
    int a_r0 = min(m0 + (c0 >> 2), M_ - 1), a_c0 = (c0 & 3) * 8;
    int a_r1 = min(m0 + (c1 >> 2), M_ - 1), a_c1 = (c1 & 3) * 8;
    int b_r0 = n0 + (c0 >> 2), b_r1 = n0 + (c1 >> 2);

    f32x4 acc[4][4];
    const f32x4 zero4 = {0.f, 0.f, 0.f, 0.f};
#pragma unroll
    for (int mi = 0; mi < 4; mi++)
#pragma unroll
        for (int ni = 0; ni < 4; ni++) acc[mi][ni] = zero4;

    for (int k0 = 0; k0 < GK; k0 += 32) {
        __syncthreads();
        load_lds16(A + (size_t)a_r0 * GK + k0 + a_c0, &As[w * 512]);
        load_lds16(A + (size_t)a_r1 * GK + k0 + a_c1, &As[2048 + w * 512]);
        load_lds16(W + (size_t)b_r0 * GK + k0 + a_c0, &Bs[w * 512]);
        load_lds16(W + (size_t)b_r1 * GK + k0 + a_c1, &Bs[2048 + w * 512]);
        __syncthreads();
        short8 af[4], bf[4];
#pragma unroll
        for (int mi = 0; mi < 4; mi++)
            af[mi] = *(const short8*)&As[(wr + mi * 16 + l16) * 32 + quad * 8];
#pragma unroll
        for (int ni = 0; ni < 4; ni++)
            bf[ni] = *(const short8*)&Bs[(wc + ni * 16 + l16) * 32 + quad * 8];
#pragma unroll
        for (int mi = 0; mi < 4; mi++)
#pragma unroll
            for (int ni = 0; ni < 4; ni++)
                acc[mi][ni] = __builtin_amdgcn_mfma_f32_16x16x32_bf16(
                    af[mi], bf[ni], acc[mi][ni], 0, 0, 0);
    }

    float bvals[4];
#pragma unroll
    for (int ni = 0; ni < 4; ni++) bvals[ni] = bias[n0 + wc + ni * 16 + l16];
#pragma unroll
    for (int mi = 0; mi < 4; mi++)
#pragma unroll
        for (int reg = 0; reg < 4; reg++) {
            int m = m0 + wr + mi * 16 + quad * 4 + reg;
            if (m < M_) {
                float* row = out + (size_t)m * C_ + n0 + wc;
#pragma unroll
                for (int ni = 0; ni < 4; ni++)
                    row[ni * 16 + l16] = acc[mi][ni][reg] + bvals[ni];
            }
        }
}

// ---------------------------------------------------------------------------
// Barrier-free MFMA flash attention, fixed-max softmax, XCD-swizzled,
// K-SPLIT x2 (flash-decode): seg0 = chunks 0..16, seg1 = chunks 17..32.
// Fixed max (m==0) makes segment partials EXACT sums -> combine just adds.
// grid = 2176 blocks (17 tiles x 64 bh x 2 segs), 4 waves each.
// Partials: po bf16 [bh*N+r][seg][64], pl f32 [bh*N+r][seg].
// ---------------------------------------------------------------------------
#define TQ 64

__global__ __launch_bounds__(256, 6) void attn_mfma(
        const unsigned short* __restrict__ qg,
        const unsigned short* __restrict__ kg,
        const unsigned short* __restrict__ vtc,
        const float* __restrict__ tab,
        unsigned short* __restrict__ po,
        float* __restrict__ pl) {
    __shared__ float tabs[34 * 33];                        // stride-33, 4.5 KB
    __shared__ __align__(16) unsigned short Pl[4][16 * 40];// 5 KB, per-wave

    int tid = threadIdx.x;
    int wave = tid >> 6, lane = tid & 63;
    int quad = lane >> 4, l16 = lane & 15;

    // XCD swizzle: all (tile,seg) blocks of one bh share blockIdx%8
    int lin = blockIdx.x;
    int xcd = lin & 7;
    int u = lin >> 3;
    int bhi = u & 7;
    int w2 = u >> 3;          // 0..33
    int tile = w2 >> 1;
    int seg = w2 & 1;
    int bh = xcd * 8 + bhi;
    int h = bh & 7;

    const unsigned short* qp = qg + (size_t)bh * N_ * HD_;
    const unsigned short* kp = kg + (size_t)bh * N_ * HD_;
    const unsigned short* vp = vtc + (size_t)bh * NCH * VCS;

    for (int t = tid; t < 1024; t += 256)
        tabs[(t >> 5) * 33 + (t & 31)] = tab[h * 1024 + t];
    __syncthreads();   // tabs ready; only barrier in the kernel

    // Q fragments (A-layout)
    int row_l = tile * TQ + wave * 16 + l16;
    int rowc = min(row_l, N_ - 1);
    short8 qf[2];
    qf[0] = *(const short8*)(qp + (size_t)rowc * HD_ + quad * 8);
    qf[1] = *(const short8*)(qp + (size_t)rowc * HD_ + 32 + quad * 8);

    // C-layout rows owned by this lane; loop-invariant bias terms
    int r0c = tile * TQ + wave * 16 + quad * 4;
    int rpx[2][4], dbb[2][4];
    bool rz[4];
#pragma unroll
    for (int g = 0; g < 2; g++) {
        int e = g * 16 + l16 - 1;                // ji = c*32 + e
        int pxo = (e < 0) ? -1 : 0;
        int pyj = e & 31;
#pragma unroll
        for (int reg = 0; reg < 4; reg++) {
            int r = r0c + reg;
            int ri = min(max(r - 1, 0), N_ - 2);
            rpx[g][reg] = (ri >> 5) - pxo;       // da = |rpx - c|
            int db = (ri & 31) - pyj;
            dbb[g][reg] = (db < 0) ? -db : db;
            if (g == 0) rz[reg] = (r == 0);
        }
    }

    f32x4 o_acc[4], l_acc;
    const f32x4 zero4 = {0.f, 0.f, 0.f, 0.f};
#pragma unroll
    for (int g2 = 0; g2 < 4; g2++) o_acc[g2] = zero4;
    l_acc = zero4;
    short8 ones;
    {
        short one_bf = (short)0x3F80;
#pragma unroll
        for (int j = 0; j < 8; j++) ones[j] = one_bf;
    }

    auto loadK = [&](int c, short8* kf) {
        int k0 = min(c * 32 + l16, N_ - 1);
        int k1 = min(c * 32 + 16 + l16, N_ - 1);
        kf[0] = *(const short8*)(kp + (size_t)k0 * HD_ + quad * 8);
        kf[1] = *(const short8*)(kp + (size_t)k0 * HD_ + 32 + quad * 8);
        kf[2] = *(const short8*)(kp + (size_t)k1 * HD_ + quad * 8);
        kf[3] = *(const short8*)(kp + (size_t)k1 * HD_ + 32 + quad * 8);
    };
    auto loadV = [&](int c, short8* vf) {
        const unsigned short* vc = vp + (size_t)c * VCS + quad * 8;
#pragma unroll
        for (int g2 = 0; g2 < 4; g2++)
            vf[g2] = *(const short8*)(vc + (g2 * 16 + l16) * 32);
    };

    auto body = [&](int c, const short8* kf, const short8* vf,
                    short8* kpre, short8* vpre, bool prefK, bool prefV,
                    bool first, bool last) {
        f32x4 s[2];
        s[0] = __builtin_amdgcn_mfma_f32_16x16x32_bf16(qf[0], kf[0], zero4, 0, 0, 0);
        s[0] = __builtin_amdgcn_mfma_f32_16x16x32_bf16(qf[1], kf[1], s[0], 0, 0, 0);
        s[1] = __builtin_amdgcn_mfma_f32_16x16x32_bf16(qf[0], kf[2], zero4, 0, 0, 0);
        s[1] = __builtin_amdgcn_mfma_f32_16x16x32_bf16(qf[1], kf[3], s[1], 0, 0, 0);
        if (prefK) loadK(c + 2, kpre);      // used 2 bodies from now

        // bias add: idx = |rpx - c|*33 + dbb  (sad + mad + ds_read)
#pragma unroll
        for (int g = 0; g < 2; g++)
#pragma unroll
            for (int reg = 0; reg < 4; reg++) {
                int da = __sad(rpx[g][reg], c, 0u);
                float bia = tabs[da * 33 + dbb[g][reg]];
                if (rz[reg]) bia = 0.f;
                if (first && g == 0 && l16 == 0) bia = 0.f;   // jj == 0 column
                s[g][reg] += bia;
            }
        if (prefV) loadV(c + 1, vpre);      // used at end of next body
        if (last) {   // keys >= N_ in final chunk (c == 32)
#pragma unroll
            for (int reg = 0; reg < 4; reg++) {
                if (l16 != 0) s[0][reg] = -1e30f;
                s[1][reg] = -1e30f;
            }
        }

        // fixed-max softmax: p = exp(s)
        float p0[4], p1[4];
#pragma unroll
        for (int reg = 0; reg < 4; reg++) {
            p0[reg] = __expf(s[0][reg]);
            p1[reg] = __expf(s[1][reg]);
        }

        // P round trip (C-layout -> A-layout), per-wave LDS, no barrier
        unsigned short* plw = &Pl[wave][0];
#pragma unroll
        for (int reg = 0; reg < 4; reg++) {
            plw[(quad * 4 + reg) * 40 + l16]      = bf16u(p0[reg]);
            plw[(quad * 4 + reg) * 40 + 16 + l16] = bf16u(p1[reg]);
        }
        short8 pf = *(const short8*)&Pl[wave][l16 * 40 + quad * 8];

        // PV + l accumulation (ones-column trick)
#pragma unroll
        for (int g2 = 0; g2 < 4; g2++)
            o_acc[g2] = __builtin_amdgcn_mfma_f32_16x16x32_bf16(pf, vf[g2], o_acc[g2], 0, 0, 0);
        l_acc = __builtin_amdgcn_mfma_f32_16x16x32_bf16(pf, ones, l_acc, 0, 0, 0);
    };

    short8 kA[4], kB[4], vA[4], vB[4];
    if (seg == 0) {
        // chunks 0..16 (17 bodies)
        loadK(0, kA); loadK(1, kB); loadV(0, vA);
        body(0, kA, vA, kA, vB, true, true, true, false);
#pragma unroll 1
        for (int c = 1; c <= 13; c += 2) {
            body(c,     kB, vB, kB, vA, true, true, false, false);
            body(c + 1, kA, vA, kA, vB, true, true, false, false);
        }
        body(15, kB, vB, nullptr, vA, false, true, false, false);
        body(16, kA, vA, nullptr, nullptr, false, false, false, false);
    } else {
        // chunks 17..32 (16 bodies)
        loadK(17, kA); loadK(18, kB); loadV(17, vA);
        body(17, kA, vA, kA, vB, true, true, false, false);
#pragma unroll 1
        for (int c = 18; c <= 28; c += 2) {
            body(c,     kB, vB, kB, vA, true, true, false, false);
            body(c + 1, kA, vA, kA, vB, true, true, false, false);
        }
        body(30, kB, vB, kB, vA, true, true, false, false);
        body(31, kA, vA, nullptr, vB, false, true, false, false);
        body(32, kB, vB, nullptr, nullptr, false, false, false, true);
    }

    // store partials (C-layout rows), NO division here
#pragma unroll
    for (int reg = 0; reg < 4; reg++) {
        int r = r0c + reg;
        if (r < N_) {
            size_t rl = (size_t)bh * N_ + r;
            unsigned short* prow = po + (rl * 2 + seg) * 64;
#pragma unroll
            for (int g2 = 0; g2 < 4; g2++)
                prow[g2 * 16 + l16] = bf16u(o_acc[g2][reg]);
            if (l16 == 0) pl[rl * 2 + seg] = l_acc[reg];
        }
    }
}

// ---------------------------------------------------------------------------
// Combine: o = (po[seg0] + po[seg1]) / (pl[seg0] + pl[seg1]) -> ob bf16
// grid = 16400 x 256: thread = (row_lin, dim)
// ---------------------------------------------------------------------------
__global__ __launch_bounds__(256) void attn_combine(
        const unsigned short* __restrict__ po, const float* __restrict__ pl,
        unsigned short* __restrict__ ob) {
    int tid = threadIdx.x;
    int row = blockIdx.x * 4 + (tid >> 6);
    int dim = tid & 63;
    size_t base = (size_t)row * 2 * 64;
    float o = bf16f(po[base + dim]) + bf16f(po[base + 64 + dim]);
    float l = pl[row * 2] + pl[row * 2 + 1];
    int b = row / (H_ * N_);
    int rem = row - b * (H_ * N_);
    int h = rem / N_;
    int r = rem - h * N_;
    ob[((size_t)b * N_ + r) * C_ + h * HD_ + dim] = bf16u(o / l);
}

// ---------------------------------------------------------------------------
extern "C" void kernel_launch(void* const* d_in, const int* in_sizes, int n_in,
                              void* d_out, int out_size, void* d_ws, size_t ws_size,
                              hipStream_t stream) {
    const float* x      = (const float*)d_in[0];
    const float* qkv_w  = (const float*)d_in[1];
    const float* proj_w = (const float*)d_in[2];
    const float* proj_b = (const float*)d_in[3];
    const float* wg_w   = (const float*)d_in[4];
    const float* wg_b   = (const float*)d_in[5];
    float* out = (float*)d_out;

    const size_t per = (size_t)B_ * H_ * N_ * HD_;   // 4,198,400 elems
    char* ws = (char*)d_ws;
    float* tab = (float*)ws;                                     // 32 KB

    // Region R: xb+wqkvb (live: casts -> gemm_qkv) overlapped with po+pl
    // (live: attn -> combine). Safe: disjoint lifetimes within one replay.
    char* R = ws + (32 << 10);
    unsigned short* xb    = (unsigned short*)R;                  // 8,396,800 B
    unsigned short* wqkvb = (unsigned short*)(R + 8396800);      // 1,572,864 B
    unsigned short* po    = (unsigned short*)R;                  // 16,793,600 B
    float*          pl    = (float*)(R + 16793600);              //    524,800 B
    char* after = R + 17318400;
    unsigned short* wprjb = (unsigned short*)after;              // 524,288 B
    unsigned short* qb    = (unsigned short*)(after + 524288);
    unsigned short* kb    = qb + per;
    unsigned short* vtc   = kb + per;                            // [bh][ch][dim][32]
    unsigned short* ob    = vtc + (size_t)B_ * H_ * NCH * VCS;   // [B][N][C] bf16

    bias_tab_kernel<<<32, 256, 0, stream>>>(wg_w, wg_b, tab);
    cast_bf16_kernel<<<(int)(per / 4 / 256), 256, 0, stream>>>(x, xb, (int)per);
    cast_bf16_kernel<<<(3 * C_ * C_) / 4 / 256, 256, 0, stream>>>(qkv_w, wqkvb, 3 * C_ * C_);
    cast_bf16_kernel<<<(C_ * C_) / 4 / 256, 256, 0, stream>>>(proj_w, wprjb, C_ * C_);
    gemm_qkv_mfma<<<dim3(12, 65), 256, 0, stream>>>(xb, wqkvb, qb, kb, vtc);
    attn_mfma<<<17 * 64 * 2, 256, 0, stream>>>(qb, kb, vtc, tab, po, pl);
    attn_combine<<<NROWS / 4, 256, 0, stream>>>(po, pl, ob);
    gemm_proj_mfma<<<dim3(4, 65), 256, 0, stream>>>(ob, wprjb, proj_b, out);
}

// Round 8
// 275.753 us; speedup vs baseline: 1.3776x; 1.3776x over previous
//
#include <hip/hip_runtime.h>
#include <hip/hip_bf16.h>
#include <math.h>

#define B_  8
#define N_  1025
#define C_  512
#define H_  8
#define HD_ 64
#define M_  (B_ * N_)   // 8200
#define NCH 33          // ceil(N_/32) key chunks
#define VCS 2048        // shorts per vtc chunk: 64 dims * 32 keys
#define NROWS (64 * N_) // 65600 (bh x row)

typedef __attribute__((ext_vector_type(8))) short short8;
typedef __attribute__((ext_vector_type(4))) float f32x4;

__device__ inline unsigned short bf16u(float x) {
    __hip_bfloat16 t = __float2bfloat16(x);
    return *(unsigned short*)&t;
}
__device__ inline float bf16f(unsigned short u) {
    return __uint_as_float(((unsigned)u) << 16);
}
__device__ inline void load_lds16(const void* g, void* l) {
    __builtin_amdgcn_global_load_lds(
        (const __attribute__((address_space(1))) unsigned int*)g,
        (__attribute__((address_space(3))) unsigned int*)l, 16, 0, 0);
}

// ---------------------------------------------------------------------------
__global__ void cast_bf16_kernel(const float* __restrict__ src,
                                 unsigned short* __restrict__ dst, int n) {
    int i4 = (blockIdx.x * blockDim.x + threadIdx.x) * 4;
    if (i4 + 3 < n) {
        float4 v = *(const float4*)(src + i4);
        ushort4 p;
        p.x = bf16u(v.x); p.y = bf16u(v.y); p.z = bf16u(v.z); p.w = bf16u(v.w);
        *(ushort4*)(dst + i4) = p;
    }
}

// ---------------------------------------------------------------------------
// Geometry bias collapses to an H x 32 x 32 table (dw=dh=0; |dpx|,|dpy| only).
// ---------------------------------------------------------------------------
__global__ void bias_tab_kernel(const float* __restrict__ wg_w,
                                const float* __restrict__ wg_b,
                                float* __restrict__ tab) {
    int idx = blockIdx.x * blockDim.x + threadIdx.x;
    if (idx >= H_ * 32 * 32) return;
    int h = idx >> 10;
    int a = (idx >> 5) & 31;
    int b = idx & 31;
    float dx = logf(fmaxf((float)a * (1.0f / 33.0f), 0.001f));
    float dy = logf(fmaxf((float)b * (1.0f / 33.0f), 0.001f));
    const float* w = wg_w + h * 64;
    float acc = wg_b[h];
#pragma unroll
    for (int k = 0; k < 8; k++) {
        float f = powf(1000.0f, -(float)k * 0.125f);
        float X = 100.0f * dx * f;
        float Y = 100.0f * dy * f;
        acc += w[k]      * sinf(X);
        acc += w[8 + k]  * sinf(Y);
        acc += w[32 + k] * cosf(X);
        acc += w[40 + k] * cosf(Y);
        acc += w[48 + k] + w[56 + k];
    }
    tab[idx] = logf(fmaxf(fmaxf(acc, 0.0f), 1e-6f));
}

// ---------------------------------------------------------------------------
// MFMA GEMM, 128x128 tile, BK=32, 4 waves. QKV variant scatters q (x0.125)
// and k to [bh][tok][64]; v goes to chunk-padded transposed vtc
// [bh][chunk][dim][32].
// ---------------------------------------------------------------------------
#define GK 512

__global__ __launch_bounds__(256) void gemm_qkv_mfma(
        const unsigned short* __restrict__ A, const unsigned short* __restrict__ W,
        unsigned short* __restrict__ qb, unsigned short* __restrict__ kb,
        unsigned short* __restrict__ vtc) {
    __shared__ __align__(16) unsigned short As[128 * 32];
    __shared__ __align__(16) unsigned short Bs[128 * 32];
    int tid = threadIdx.x;
    int w = tid >> 6, lane = tid & 63;
    int quad = lane >> 4, l16 = lane & 15;
    int m0 = blockIdx.y * 128;
    int n0 = blockIdx.x * 128;
    int wr = (w >> 1) * 64, wc = (w & 1) * 64;

    int c0 = tid, c1 = tid + 256;
    int a_r0 = min(m0 + (c0 >> 2), M_ - 1), a_c0 = (c0 & 3) * 8;
    int a_r1 = min(m0 + (c1 >> 2), M_ - 1), a_c1 = (c1 & 3) * 8;
    int b_r0 = n0 + (c0 >> 2), b_r1 = n0 + (c1 >> 2);

    f32x4 acc[4][4];
    const f32x4 zero4 = {0.f, 0.f, 0.f, 0.f};
#pragma unroll
    for (int mi = 0; mi < 4; mi++)
#pragma unroll
        for (int ni = 0; ni < 4; ni++) acc[mi][ni] = zero4;

    for (int k0 = 0; k0 < GK; k0 += 32) {
        __syncthreads();
        load_lds16(A + (size_t)a_r0 * GK + k0 + a_c0, &As[w * 512]);
        load_lds16(A + (size_t)a_r1 * GK + k0 + a_c1, &As[2048 + w * 512]);
        load_lds16(W + (size_t)b_r0 * GK + k0 + a_c0, &Bs[w * 512]);
        load_lds16(W + (size_t)b_r1 * GK + k0 + a_c1, &Bs[2048 + w * 512]);
        __syncthreads();
        short8 af[4], bf[4];
#pragma unroll
        for (int mi = 0; mi < 4; mi++)
            af[mi] = *(const short8*)&As[(wr + mi * 16 + l16) * 32 + quad * 8];
#pragma unroll
        for (int ni = 0; ni < 4; ni++)
            bf[ni] = *(const short8*)&Bs[(wc + ni * 16 + l16) * 32 + quad * 8];
#pragma unroll
        for (int mi = 0; mi < 4; mi++)
#pragma unroll
            for (int ni = 0; ni < 4; ni++)
                acc[mi][ni] = __builtin_amdgcn_mfma_f32_16x16x32_bf16(
                    af[mi], bf[ni], acc[mi][ni], 0, 0, 0);
    }

    int which = n0 >> 9;                       // 0=q 1=k 2=v
    int h = ((n0 + wc) >> 6) & 7;
    if (which < 2) {
        unsigned short* dst = (which == 0) ? qb : kb;
        float sc = (which == 0) ? 0.125f : 1.0f;
#pragma unroll
        for (int mi = 0; mi < 4; mi++)
#pragma unroll
            for (int reg = 0; reg < 4; reg++) {
                int m = m0 + wr + mi * 16 + quad * 4 + reg;
                if (m < M_) {
                    int bb = m / N_;
                    int i  = m - bb * N_;
                    unsigned short* row = dst + ((size_t)(bb * H_ + h) * N_ + i) * HD_;
#pragma unroll
                    for (int ni = 0; ni < 4; ni++)
                        row[ni * 16 + l16] = bf16u(acc[mi][ni][reg] * sc);
                }
            }
    } else {
#pragma unroll
        for (int mi = 0; mi < 4; mi++)
#pragma unroll
            for (int reg = 0; reg < 4; reg++) {
                int m = m0 + wr + mi * 16 + quad * 4 + reg;
                if (m < M_) {
                    int bb = m / N_;
                    int i  = m - bb * N_;
                    int ch = i >> 5, key = i & 31;
                    size_t base = ((size_t)(bb * H_ + h) * NCH + ch) * VCS + key;
#pragma unroll
                    for (int ni = 0; ni < 4; ni++)
                        vtc[base + (size_t)(ni * 16 + l16) * 32] = bf16u(acc[mi][ni][reg]);
                }
            }
    }
}

__global__ __launch_bounds__(256) void gemm_proj_mfma(
        const unsigned short* __restrict__ A, const unsigned short* __restrict__ W,
        const float* __restrict__ bias, float* __restrict__ out) {
    __shared__ __align__(16) unsigned short As[128 * 32];
    __shared__ __align__(16) unsigned short Bs[128 * 32];
    int tid = threadIdx.x;
    int w = tid >> 6, lane = tid & 63;
    int quad = lane >> 4, l16 = lane & 15;
    int m0 = blockIdx.y * 128;
    int n0 = blockIdx.x * 128;
    int wr = (w >> 1) * 64, wc = (w & 1) * 64;

    int c0 = tid, c1 = tid + 256;
    int a_r0 = min(m0 + (c0 >> 2), M_ - 1), a_c0 = (c0 & 3) * 8;
    int a_r1 = min(m0 + (c1 >> 2), M_ - 1), a_c1 = (c1 & 3) * 8;
    int b_r0 = n0 + (c0 >> 2), b_r1 = n0 + (c1 >> 2);

    f32x4 acc[4][4];
    const f32x4 zero4 = {0.f, 0.f, 0.f, 0.f};
#pragma unroll
    for (int mi = 0; mi < 4; mi++)
#pragma unroll
        for (int ni = 0; ni < 4; ni++) acc[mi][ni] = zero4;

    for (int k0 = 0; k0 < GK; k0 += 32) {
        __syncthreads();
        load_lds16(A + (size_t)a_r0 * GK + k0 + a_c0, &As[w * 512]);
        load_lds16(A + (size_t)a_r1 * GK + k0 + a_c1, &As[2048 + w * 512]);
        load_lds16(W + (size_t)b_r0 * GK + k0 + a_c0, &Bs[w * 512]);
        load_lds16(W + (size_t)b_r1 * GK + k0 + a_c1, &Bs[2048 + w * 512]);
        __syncthreads();
        short8 af[4], bf[4];
#pragma unroll
        for (int mi = 0; mi < 4; mi++)
            af[mi] = *(const short8*)&As[(wr + mi * 16 + l16) * 32 + quad * 8];
#pragma unroll
        for (int ni = 0; ni < 4; ni++)
            bf[ni] = *(const short8*)&Bs[(wc + ni * 16 + l16) * 32 + quad * 8];
#pragma unroll
        for (int mi = 0; mi < 4; mi++)
#pragma unroll
            for (int ni = 0; ni < 4; ni++)
                acc[mi][ni] = __builtin_amdgcn_mfma_f32_16x16x32_bf16(
                    af[mi], bf[ni], acc[mi][ni], 0, 0, 0);
    }

    float bvals[4];
#pragma unroll
    for (int ni = 0; ni < 4; ni++) bvals[ni] = bias[n0 + wc + ni * 16 + l16];
#pragma unroll
    for (int mi = 0; mi < 4; mi++)
#pragma unroll
        for (int reg = 0; reg < 4; reg++) {
            int m = m0 + wr + mi * 16 + quad * 4 + reg;
            if (m < M_) {
                float* row = out + (size_t)m * C_ + n0 + wc;
#pragma unroll
                for (int ni = 0; ni < 4; ni++)
                    row[ni * 16 + l16] = acc[mi][ni][reg] + bvals[ni];
            }
        }
}

// ---------------------------------------------------------------------------
// Barrier-free MFMA flash attention, fixed-max softmax, XCD-swizzled,
// K-SPLIT x2 (flash-decode): seg0 = chunks 0..16, seg1 = chunks 17..32.
// Fixed max (m==0) makes segment partials EXACT sums -> combine just adds.
// grid = 2176 blocks (17 tiles x 64 bh x 2 segs), 4 waves each.
// NOTE: no min-waves launch bound — R7's (256,6) forced VGPR=40 and spilled
// the register K/V double-buffers to scratch (FETCH 421 MB, 2x slower).
// ---------------------------------------------------------------------------
#define TQ 64

__global__ __launch_bounds__(256) void attn_mfma(
        const unsigned short* __restrict__ qg,
        const unsigned short* __restrict__ kg,
        const unsigned short* __restrict__ vtc,
        const float* __restrict__ tab,
        unsigned short* __restrict__ po,
        float* __restrict__ pl) {
    __shared__ float tabs[34 * 33];                        // stride-33, 4.5 KB
    __shared__ __align__(16) unsigned short Pl[4][16 * 40];// 5 KB, per-wave

    int tid = threadIdx.x;
    int wave = tid >> 6, lane = tid & 63;
    int quad = lane >> 4, l16 = lane & 15;

    // XCD swizzle: all (tile,seg) blocks of one bh share blockIdx%8
    int lin = blockIdx.x;
    int xcd = lin & 7;
    int u = lin >> 3;
    int bhi = u & 7;
    int w2 = u >> 3;          // 0..33
    int tile = w2 >> 1;
    int seg = w2 & 1;
    int bh = xcd * 8 + bhi;
    int h = bh & 7;

    const unsigned short* qp = qg + (size_t)bh * N_ * HD_;
    const unsigned short* kp = kg + (size_t)bh * N_ * HD_;
    const unsigned short* vp = vtc + (size_t)bh * NCH * VCS;

    for (int t = tid; t < 1024; t += 256)
        tabs[(t >> 5) * 33 + (t & 31)] = tab[h * 1024 + t];
    __syncthreads();   // tabs ready; only barrier in the kernel

    // Q fragments (A-layout)
    int row_l = tile * TQ + wave * 16 + l16;
    int rowc = min(row_l, N_ - 1);
    short8 qf[2];
    qf[0] = *(const short8*)(qp + (size_t)rowc * HD_ + quad * 8);
    qf[1] = *(const short8*)(qp + (size_t)rowc * HD_ + 32 + quad * 8);

    // C-layout rows owned by this lane; loop-invariant bias terms
    int r0c = tile * TQ + wave * 16 + quad * 4;
    int rpx[2][4], dbb[2][4];
    bool rz[4];
#pragma unroll
    for (int g = 0; g < 2; g++) {
        int e = g * 16 + l16 - 1;                // ji = c*32 + e
        int pxo = (e < 0) ? -1 : 0;
        int pyj = e & 31;
#pragma unroll
        for (int reg = 0; reg < 4; reg++) {
            int r = r0c + reg;
            int ri = min(max(r - 1, 0), N_ - 2);
            rpx[g][reg] = (ri >> 5) - pxo;       // da = |rpx - c|
            int db = (ri & 31) - pyj;
            dbb[g][reg] = (db < 0) ? -db : db;
            if (g == 0) rz[reg] = (r == 0);
        }
    }

    f32x4 o_acc[4], l_acc;
    const f32x4 zero4 = {0.f, 0.f, 0.f, 0.f};
#pragma unroll
    for (int g2 = 0; g2 < 4; g2++) o_acc[g2] = zero4;
    l_acc = zero4;
    short8 ones;
    {
        short one_bf = (short)0x3F80;
#pragma unroll
        for (int j = 0; j < 8; j++) ones[j] = one_bf;
    }

    auto loadK = [&](int c, short8* kf) {
        int k0 = min(c * 32 + l16, N_ - 1);
        int k1 = min(c * 32 + 16 + l16, N_ - 1);
        kf[0] = *(const short8*)(kp + (size_t)k0 * HD_ + quad * 8);
        kf[1] = *(const short8*)(kp + (size_t)k0 * HD_ + 32 + quad * 8);
        kf[2] = *(const short8*)(kp + (size_t)k1 * HD_ + quad * 8);
        kf[3] = *(const short8*)(kp + (size_t)k1 * HD_ + 32 + quad * 8);
    };
    auto loadV = [&](int c, short8* vf) {
        const unsigned short* vc = vp + (size_t)c * VCS + quad * 8;
#pragma unroll
        for (int g2 = 0; g2 < 4; g2++)
            vf[g2] = *(const short8*)(vc + (g2 * 16 + l16) * 32);
    };

    auto body = [&](int c, const short8* kf, const short8* vf,
                    short8* kpre, short8* vpre, bool prefK, bool prefV,
                    bool first, bool last) {
        f32x4 s[2];
        s[0] = __builtin_amdgcn_mfma_f32_16x16x32_bf16(qf[0], kf[0], zero4, 0, 0, 0);
        s[0] = __builtin_amdgcn_mfma_f32_16x16x32_bf16(qf[1], kf[1], s[0], 0, 0, 0);
        s[1] = __builtin_amdgcn_mfma_f32_16x16x32_bf16(qf[0], kf[2], zero4, 0, 0, 0);
        s[1] = __builtin_amdgcn_mfma_f32_16x16x32_bf16(qf[1], kf[3], s[1], 0, 0, 0);
        if (prefK) loadK(c + 2, kpre);      // used 2 bodies from now

        // bias add: idx = |rpx - c|*33 + dbb  (sad + mad + ds_read)
#pragma unroll
        for (int g = 0; g < 2; g++)
#pragma unroll
            for (int reg = 0; reg < 4; reg++) {
                int da = __sad(rpx[g][reg], c, 0u);
                float bia = tabs[da * 33 + dbb[g][reg]];
                if (rz[reg]) bia = 0.f;
                if (first && g == 0 && l16 == 0) bia = 0.f;   // jj == 0 column
                s[g][reg] += bia;
            }
        if (prefV) loadV(c + 1, vpre);      // used at end of next body
        if (last) {   // keys >= N_ in final chunk (c == 32)
#pragma unroll
            for (int reg = 0; reg < 4; reg++) {
                if (l16 != 0) s[0][reg] = -1e30f;
                s[1][reg] = -1e30f;
            }
        }

        // fixed-max softmax: p = exp(s)
        float p0[4], p1[4];
#pragma unroll
        for (int reg = 0; reg < 4; reg++) {
            p0[reg] = __expf(s[0][reg]);
            p1[reg] = __expf(s[1][reg]);
        }

        // P round trip (C-layout -> A-layout), per-wave LDS, no barrier
        unsigned short* plw = &Pl[wave][0];
#pragma unroll
        for (int reg = 0; reg < 4; reg++) {
            plw[(quad * 4 + reg) * 40 + l16]      = bf16u(p0[reg]);
            plw[(quad * 4 + reg) * 40 + 16 + l16] = bf16u(p1[reg]);
        }
        short8 pf = *(const short8*)&Pl[wave][l16 * 40 + quad * 8];

        // PV + l accumulation (ones-column trick)
#pragma unroll
        for (int g2 = 0; g2 < 4; g2++)
            o_acc[g2] = __builtin_amdgcn_mfma_f32_16x16x32_bf16(pf, vf[g2], o_acc[g2], 0, 0, 0);
        l_acc = __builtin_amdgcn_mfma_f32_16x16x32_bf16(pf, ones, l_acc, 0, 0, 0);
    };

    short8 kA[4], kB[4], vA[4], vB[4];
    if (seg == 0) {
        // chunks 0..16 (17 bodies)
        loadK(0, kA); loadK(1, kB); loadV(0, vA);
        body(0, kA, vA, kA, vB, true, true, true, false);
#pragma unroll 1
        for (int c = 1; c <= 13; c += 2) {
            body(c,     kB, vB, kB, vA, true, true, false, false);
            body(c + 1, kA, vA, kA, vB, true, true, false, false);
        }
        body(15, kB, vB, nullptr, vA, false, true, false, false);
        body(16, kA, vA, nullptr, nullptr, false, false, false, false);
    } else {
        // chunks 17..32 (16 bodies)
        loadK(17, kA); loadK(18, kB); loadV(17, vA);
        body(17, kA, vA, kA, vB, true, true, false, false);
#pragma unroll 1
        for (int c = 18; c <= 28; c += 2) {
            body(c,     kB, vB, kB, vA, true, true, false, false);
            body(c + 1, kA, vA, kA, vB, true, true, false, false);
        }
        body(30, kB, vB, kB, vA, true, true, false, false);
        body(31, kA, vA, nullptr, vB, false, true, false, false);
        body(32, kB, vB, nullptr, nullptr, false, false, false, true);
    }

    // store partials (C-layout rows), NO division here
#pragma unroll
    for (int reg = 0; reg < 4; reg++) {
        int r = r0c + reg;
        if (r < N_) {
            size_t rl = (size_t)bh * N_ + r;
            unsigned short* prow = po + (rl * 2 + seg) * 64;
#pragma unroll
            for (int g2 = 0; g2 < 4; g2++)
                prow[g2 * 16 + l16] = bf16u(o_acc[g2][reg]);
            if (l16 == 0) pl[rl * 2 + seg] = l_acc[reg];
        }
    }
}

// ---------------------------------------------------------------------------
// Combine: o = (po[seg0] + po[seg1]) / (pl[seg0] + pl[seg1]) -> ob bf16
// grid = 16400 x 256: thread = (row_lin, dim)
// ---------------------------------------------------------------------------
__global__ __launch_bounds__(256) void attn_combine(
        const unsigned short* __restrict__ po, const float* __restrict__ pl,
        unsigned short* __restrict__ ob) {
    int tid = threadIdx.x;
    int row = blockIdx.x * 4 + (tid >> 6);
    int dim = tid & 63;
    size_t base = (size_t)row * 2 * 64;
    float o = bf16f(po[base + dim]) + bf16f(po[base + 64 + dim]);
    float l = pl[row * 2] + pl[row * 2 + 1];
    int b = row / (H_ * N_);
    int rem = row - b * (H_ * N_);
    int h = rem / N_;
    int r = rem - h * N_;
    ob[((size_t)b * N_ + r) * C_ + h * HD_ + dim] = bf16u(o / l);
}

// ---------------------------------------------------------------------------
extern "C" void kernel_launch(void* const* d_in, const int* in_sizes, int n_in,
                              void* d_out, int out_size, void* d_ws, size_t ws_size,
                              hipStream_t stream) {
    const float* x      = (const float*)d_in[0];
    const float* qkv_w  = (const float*)d_in[1];
    const float* proj_w = (const float*)d_in[2];
    const float* proj_b = (const float*)d_in[3];
    const float* wg_w   = (const float*)d_in[4];
    const float* wg_b   = (const float*)d_in[5];
    float* out = (float*)d_out;

    const size_t per = (size_t)B_ * H_ * N_ * HD_;   // 4,198,400 elems
    char* ws = (char*)d_ws;
    float* tab = (float*)ws;                                     // 32 KB

    // Region R: xb+wqkvb (live: casts -> gemm_qkv) overlapped with po+pl
    // (live: attn -> combine). Safe: disjoint lifetimes within one replay.
    char* R = ws + (32 << 10);
    unsigned short* xb    = (unsigned short*)R;                  // 8,396,800 B
    unsigned short* wqkvb = (unsigned short*)(R + 8396800);      // 1,572,864 B
    unsigned short* po    = (unsigned short*)R;                  // 16,793,600 B
    float*          pl    = (float*)(R + 16793600);              //    524,800 B
    char* after = R + 17318400;
    unsigned short* wprjb = (unsigned short*)after;              // 524,288 B
    unsigned short* qb    = (unsigned short*)(after + 524288);
    unsigned short* kb    = qb + per;
    unsigned short* vtc   = kb + per;                            // [bh][ch][dim][32]
    unsigned short* ob    = vtc + (size_t)B_ * H_ * NCH * VCS;   // [B][N][C] bf16

    bias_tab_kernel<<<32, 256, 0, stream>>>(wg_w, wg_b, tab);
    cast_bf16_kernel<<<(int)(per / 4 / 256), 256, 0, stream>>>(x, xb, (int)per);
    cast_bf16_kernel<<<(3 * C_ * C_) / 4 / 256, 256, 0, stream>>>(qkv_w, wqkvb, 3 * C_ * C_);
    cast_bf16_kernel<<<(C_ * C_) / 4 / 256, 256, 0, stream>>>(proj_w, wprjb, C_ * C_);
    gemm_qkv_mfma<<<dim3(12, 65), 256, 0, stream>>>(xb, wqkvb, qb, kb, vtc);
    attn_mfma<<<17 * 64 * 2, 256, 0, stream>>>(qb, kb, vtc, tab, po, pl);
    attn_combine<<<NROWS / 4, 256, 0, stream>>>(po, pl, ob);
    gemm_proj_mfma<<<dim3(4, 65), 256, 0, stream>>>(ob, wprjb, proj_b, out);
}

// Round 9
// 263.935 us; speedup vs baseline: 1.4393x; 1.0448x over previous
//
#include <hip/hip_runtime.h>
#include <hip/hip_bf16.h>
#include <math.h>

#define B_  8
#define N_  1025
#define C_  512
#define H_  8
#define HD_ 64
#define M_  (B_ * N_)   // 8200
#define NCH 33          // ceil(N_/32) key chunks
#define VCS 2048        // shorts per vtc chunk: 64 dims * 32 keys
#define NROWS (64 * N_) // 65600 (bh x row)

typedef __attribute__((ext_vector_type(8))) short short8;
typedef __attribute__((ext_vector_type(4))) float f32x4;

__device__ inline unsigned short bf16u(float x) {
    __hip_bfloat16 t = __float2bfloat16(x);
    return *(unsigned short*)&t;
}
__device__ inline float bf16f(unsigned short u) {
    return __uint_as_float(((unsigned)u) << 16);
}
__device__ inline void load_lds16(const void* g, void* l) {
    __builtin_amdgcn_global_load_lds(
        (const __attribute__((address_space(1))) unsigned int*)g,
        (__attribute__((address_space(3))) unsigned int*)l, 16, 0, 0);
}

// ---------------------------------------------------------------------------
// Fused prep: blocks 0..31 build the H x 32 x 32 bias table (geometry bias
// collapses: dw=dh=0, depends only on |dpx|,|dpy|); remaining blocks cast
// x / qkv_w / proj_w fp32 -> bf16.
// ---------------------------------------------------------------------------
#define PER_ ((size_t)B_ * H_ * N_ * HD_)      // 4,198,400
#define SZ_QKVW (3 * C_ * C_)                  //   786,432
#define SZ_PRJW (C_ * C_)                      //   262,144
#define CAST_BLKS ((4198400 + 786432 + 262144) / 4 / 256)   // 5124

__global__ void prep_kernel(const float* __restrict__ x,
                            const float* __restrict__ qkv_w,
                            const float* __restrict__ proj_w,
                            const float* __restrict__ wg_w,
                            const float* __restrict__ wg_b,
                            unsigned short* __restrict__ xb,
                            unsigned short* __restrict__ wqkvb,
                            unsigned short* __restrict__ wprjb,
                            float* __restrict__ tab) {
    int blk = blockIdx.x;
    int tid = threadIdx.x;
    if (blk < 32) {
        int idx = blk * 256 + tid;
        int h = idx >> 10;
        int a = (idx >> 5) & 31;
        int b = idx & 31;
        float dx = logf(fmaxf((float)a * (1.0f / 33.0f), 0.001f));
        float dy = logf(fmaxf((float)b * (1.0f / 33.0f), 0.001f));
        const float* w = wg_w + h * 64;
        float acc = wg_b[h];
#pragma unroll
        for (int k = 0; k < 8; k++) {
            float f = powf(1000.0f, -(float)k * 0.125f);
            float X = 100.0f * dx * f;
            float Y = 100.0f * dy * f;
            acc += w[k]      * sinf(X);
            acc += w[8 + k]  * sinf(Y);
            acc += w[32 + k] * cosf(X);
            acc += w[40 + k] * cosf(Y);
            acc += w[48 + k] + w[56 + k];
        }
        tab[idx] = logf(fmaxf(fmaxf(acc, 0.0f), 1e-6f));
        return;
    }
    long i4 = ((long)(blk - 32) * 256 + tid) * 4;
    const float* src;
    unsigned short* dst;
    long off;
    if (i4 < (long)PER_)                    { src = x;      dst = xb;    off = i4; }
    else if (i4 < (long)PER_ + SZ_QKVW)     { src = qkv_w;  dst = wqkvb; off = i4 - PER_; }
    else                                    { src = proj_w; dst = wprjb; off = i4 - PER_ - SZ_QKVW; }
    float4 v = *(const float4*)(src + off);
    ushort4 p;
    p.x = bf16u(v.x); p.y = bf16u(v.y); p.z = bf16u(v.z); p.w = bf16u(v.w);
    *(ushort4*)(dst + off) = p;
}

// ---------------------------------------------------------------------------
// MFMA GEMM, 128x128 tile, BK=32, 4 waves. q/k blocks use swapped-operand
// MFMA so each lane holds 4 consecutive features -> ushort4 stores.
// v blocks keep the original order and scatter to chunked vtc [bh][ch][dim][32].
// ---------------------------------------------------------------------------
#define GK 512

__global__ __launch_bounds__(256) void gemm_qkv_mfma(
        const unsigned short* __restrict__ A, const unsigned short* __restrict__ W,
        unsigned short* __restrict__ qb, unsigned short* __restrict__ kb,
        unsigned short* __restrict__ vtc) {
    __shared__ __align__(16) unsigned short As[128 * 32];
    __shared__ __align__(16) unsigned short Bs[128 * 32];
    int tid = threadIdx.x;
    int w = tid >> 6, lane = tid & 63;
    int quad = lane >> 4, l16 = lane & 15;
    int m0 = blockIdx.y * 128;
    int n0 = blockIdx.x * 128;
    int wr = (w >> 1) * 64, wc = (w & 1) * 64;

    int c0 = tid, c1 = tid + 256;
    int a_r0 = min(m0 + (c0 >> 2), M_ - 1), a_c0 = (c0 & 3) * 8;
    int a_r1 = min(m0 + (c1 >> 2), M_ - 1), a_c1 = (c1 & 3) * 8;
    int b_r0 = n0 + (c0 >> 2), b_r1 = n0 + (c1 >> 2);

    int which = n0 >> 9;                       // 0=q 1=k 2=v (uniform per block)
    int h = ((n0 + wc) >> 6) & 7;

    f32x4 acc[4][4];
    const f32x4 zero4 = {0.f, 0.f, 0.f, 0.f};
#pragma unroll
    for (int mi = 0; mi < 4; mi++)
#pragma unroll
        for (int ni = 0; ni < 4; ni++) acc[mi][ni] = zero4;

    if (which < 2) {
        // ---- swapped-operand loop: acc[mi][ni] = D[n][m] (lane: m=l16) ----
        for (int k0 = 0; k0 < GK; k0 += 32) {
            __syncthreads();
            load_lds16(A + (size_t)a_r0 * GK + k0 + a_c0, &As[w * 512]);
            load_lds16(A + (size_t)a_r1 * GK + k0 + a_c1, &As[2048 + w * 512]);
            load_lds16(W + (size_t)b_r0 * GK + k0 + a_c0, &Bs[w * 512]);
            load_lds16(W + (size_t)b_r1 * GK + k0 + a_c1, &Bs[2048 + w * 512]);
            __syncthreads();
            short8 af[4], bf[4];
#pragma unroll
            for (int mi = 0; mi < 4; mi++)
                af[mi] = *(const short8*)&As[(wr + mi * 16 + l16) * 32 + quad * 8];
#pragma unroll
            for (int ni = 0; ni < 4; ni++)
                bf[ni] = *(const short8*)&Bs[(wc + ni * 16 + l16) * 32 + quad * 8];
#pragma unroll
            for (int mi = 0; mi < 4; mi++)
#pragma unroll
                for (int ni = 0; ni < 4; ni++)
                    acc[mi][ni] = __builtin_amdgcn_mfma_f32_16x16x32_bf16(
                        bf[ni], af[mi], acc[mi][ni], 0, 0, 0);
        }
        unsigned short* dst = (which == 0) ? qb : kb;
        float sc = (which == 0) ? 0.125f : 1.0f;
#pragma unroll
        for (int mi = 0; mi < 4; mi++) {
            int m = m0 + wr + mi * 16 + l16;
            if (m < M_) {
                int bb = m / N_;
                int i  = m - bb * N_;
                unsigned short* row = dst + ((size_t)(bb * H_ + h) * N_ + i) * HD_;
#pragma unroll
                for (int ni = 0; ni < 4; ni++) {
                    ushort4 pk;
                    pk.x = bf16u(acc[mi][ni][0] * sc);
                    pk.y = bf16u(acc[mi][ni][1] * sc);
                    pk.z = bf16u(acc[mi][ni][2] * sc);
                    pk.w = bf16u(acc[mi][ni][3] * sc);
                    *(ushort4*)(row + ni * 16 + quad * 4) = pk;
                }
            }
        }
    } else {
        // ---- original-order loop: acc = D[m][n] (lane: n=l16) ----
        for (int k0 = 0; k0 < GK; k0 += 32) {
            __syncthreads();
            load_lds16(A + (size_t)a_r0 * GK + k0 + a_c0, &As[w * 512]);
            load_lds16(A + (size_t)a_r1 * GK + k0 + a_c1, &As[2048 + w * 512]);
            load_lds16(W + (size_t)b_r0 * GK + k0 + a_c0, &Bs[w * 512]);
            load_lds16(W + (size_t)b_r1 * GK + k0 + a_c1, &Bs[2048 + w * 512]);
            __syncthreads();
            short8 af[4], bf[4];
#pragma unroll
            for (int mi = 0; mi < 4; mi++)
                af[mi] = *(const short8*)&As[(wr + mi * 16 + l16) * 32 + quad * 8];
#pragma unroll
            for (int ni = 0; ni < 4; ni++)
                bf[ni] = *(const short8*)&Bs[(wc + ni * 16 + l16) * 32 + quad * 8];
#pragma unroll
            for (int mi = 0; mi < 4; mi++)
#pragma unroll
                for (int ni = 0; ni < 4; ni++)
                    acc[mi][ni] = __builtin_amdgcn_mfma_f32_16x16x32_bf16(
                        af[mi], bf[ni], acc[mi][ni], 0, 0, 0);
        }
#pragma unroll
        for (int mi = 0; mi < 4; mi++)
#pragma unroll
            for (int reg = 0; reg < 4; reg++) {
                int m = m0 + wr + mi * 16 + quad * 4 + reg;
                if (m < M_) {
                    int bb = m / N_;
                    int i  = m - bb * N_;
                    int ch = i >> 5, key = i & 31;
                    size_t base = ((size_t)(bb * H_ + h) * NCH + ch) * VCS + key;
#pragma unroll
                    for (int ni = 0; ni < 4; ni++)
                        vtc[base + (size_t)(ni * 16 + l16) * 32] = bf16u(acc[mi][ni][reg]);
                }
            }
    }
}

__global__ __launch_bounds__(256) void gemm_proj_mfma(
        const unsigned short* __restrict__ A, const unsigned short* __restrict__ W,
        const float* __restrict__ bias, float* __restrict__ out) {
    __shared__ __align__(16) unsigned short As[128 * 32];
    __shared__ __align__(16) unsigned short Bs[128 * 32];
    int tid = threadIdx.x;
    int w = tid >> 6, lane = tid & 63;
    int quad = lane >> 4, l16 = lane & 15;
    int m0 = blockIdx.y * 128;
    int n0 = blockIdx.x * 128;
    int wr = (w >> 1) * 64, wc = (w & 1) * 64;

    int c0 = tid, c1 = tid + 256;
    int a_r0 = min(m0 + (c0 >> 2), M_ - 1), a_c0 = (c0 & 3) * 8;
    int a_r1 = min(m0 + (c1 >> 2), M_ - 1), a_c1 = (c1 & 3) * 8;
    int b_r0 = n0 + (c0 >> 2), b_r1 = n0 + (c1 >> 2);

    f32x4 acc[4][4];
    const f32x4 zero4 = {0.f, 0.f, 0.f, 0.f};
#pragma unroll
    for (int mi = 0; mi < 4; mi++)
#pragma unroll
        for (int ni = 0; ni < 4; ni++) acc[mi][ni] = zero4;

    for (int k0 = 0; k0 < GK; k0 += 32) {
        __syncthreads();
        load_lds16(A + (size_t)a_r0 * GK + k0 + a_c0, &As[w * 512]);
        load_lds16(A + (size_t)a_r1 * GK + k0 + a_c1, &As[2048 + w * 512]);
        load_lds16(W + (size_t)b_r0 * GK + k0 + a_c0, &Bs[w * 512]);
        load_lds16(W + (size_t)b_r1 * GK + k0 + a_c1, &Bs[2048 + w * 512]);
        __syncthreads();
        short8 af[4], bf[4];
#pragma unroll
        for (int mi = 0; mi < 4; mi++)
            af[mi] = *(const short8*)&As[(wr + mi * 16 + l16) * 32 + quad * 8];
#pragma unroll
        for (int ni = 0; ni < 4; ni++)
            bf[ni] = *(const short8*)&Bs[(wc + ni * 16 + l16) * 32 + quad * 8];
#pragma unroll
        for (int mi = 0; mi < 4; mi++)
#pragma unroll
            for (int ni = 0; ni < 4; ni++)
                acc[mi][ni] = __builtin_amdgcn_mfma_f32_16x16x32_bf16(
                    af[mi], bf[ni], acc[mi][ni], 0, 0, 0);
    }

    float bvals[4];
#pragma unroll
    for (int ni = 0; ni < 4; ni++) bvals[ni] = bias[n0 + wc + ni * 16 + l16];
#pragma unroll
    for (int mi = 0; mi < 4; mi++)
#pragma unroll
        for (int reg = 0; reg < 4; reg++) {
            int m = m0 + wr + mi * 16 + quad * 4 + reg;
            if (m < M_) {
                float* row = out + (size_t)m * C_ + n0 + wc;
#pragma unroll
                for (int ni = 0; ni < 4; ni++)
                    row[ni * 16 + l16] = acc[mi][ni][reg] + bvals[ni];
            }
        }
}

// ---------------------------------------------------------------------------
// Barrier-free MFMA flash attention, fixed-max softmax, XCD-swizzled,
// K-split x2, and SOFTWARE-PIPELINED P: body c reads P(c-1) at its top
// (covered by QK+PV MFMAs), does PV(c-1) mid-body, writes P(c) at the end.
// exp/cvt/LDS turnaround are off the MFMA critical path. Bias table reads
// hoisted to body top. Clamps only in the final (partial) chunk.
// ---------------------------------------------------------------------------
#define TQ 64

__global__ __launch_bounds__(256) void attn_mfma(
        const unsigned short* __restrict__ qg,
        const unsigned short* __restrict__ kg,
        const unsigned short* __restrict__ vtc,
        const float* __restrict__ tab,
        unsigned short* __restrict__ po,
        float* __restrict__ pl) {
    __shared__ float tabs[34 * 33];                           // 4.5 KB
    __shared__ __align__(16) unsigned short Pl[4][2][16 * 40];// 10.2 KB

    int tid = threadIdx.x;
    int wave = tid >> 6, lane = tid & 63;
    int quad = lane >> 4, l16 = lane & 15;

    // XCD swizzle: all (tile,seg) blocks of one bh share blockIdx%8
    int lin = blockIdx.x;
    int xcd = lin & 7;
    int u = lin >> 3;
    int bhi = u & 7;
    int w2 = u >> 3;          // 0..33
    int tile = w2 >> 1;
    int seg = w2 & 1;
    int bh = xcd * 8 + bhi;
    int h = bh & 7;

    const unsigned short* qp = qg + (size_t)bh * N_ * HD_;
    const unsigned short* kp = kg + (size_t)bh * N_ * HD_;
    const unsigned short* vp = vtc + (size_t)bh * NCH * VCS;

    for (int t = tid; t < 1024; t += 256)
        tabs[(t >> 5) * 33 + (t & 31)] = tab[h * 1024 + t];
    __syncthreads();   // tabs ready; only barrier in the kernel

    // Q fragments (A-layout)
    int row_l = tile * TQ + wave * 16 + l16;
    int rowc = min(row_l, N_ - 1);
    short8 qf[2];
    qf[0] = *(const short8*)(qp + (size_t)rowc * HD_ + quad * 8);
    qf[1] = *(const short8*)(qp + (size_t)rowc * HD_ + 32 + quad * 8);

    // C-layout rows owned by this lane; loop-invariant bias terms
    int r0c = tile * TQ + wave * 16 + quad * 4;
    int rpx[2][4], dbb[2][4];
    bool rz[4];
#pragma unroll
    for (int g = 0; g < 2; g++) {
        int e = g * 16 + l16 - 1;                // ji = c*32 + e
        int pxo = (e < 0) ? -1 : 0;
        int pyj = e & 31;
#pragma unroll
        for (int reg = 0; reg < 4; reg++) {
            int r = r0c + reg;
            int ri = min(max(r - 1, 0), N_ - 2);
            rpx[g][reg] = (ri >> 5) - pxo;       // da = |rpx - c|
            int db = (ri & 31) - pyj;
            dbb[g][reg] = (db < 0) ? -db : db;
            if (g == 0) rz[reg] = (r == 0);
        }
    }

    f32x4 o_acc[4], l_acc;
    const f32x4 zero4 = {0.f, 0.f, 0.f, 0.f};
#pragma unroll
    for (int g2 = 0; g2 < 4; g2++) o_acc[g2] = zero4;
    l_acc = zero4;
    short8 ones;
    {
        short one_bf = (short)0x3F80;
#pragma unroll
        for (int j = 0; j < 8; j++) ones[j] = one_bf;
    }

    auto loadK = [&](int c, short8* kf) {        // no clamp (masked if partial)
        const unsigned short* kr = kp + (size_t)c * 32 * HD_;
        kf[0] = *(const short8*)(kr + (size_t)l16 * HD_ + quad * 8);
        kf[1] = *(const short8*)(kr + (size_t)l16 * HD_ + 32 + quad * 8);
        kf[2] = *(const short8*)(kr + (size_t)(16 + l16) * HD_ + quad * 8);
        kf[3] = *(const short8*)(kr + (size_t)(16 + l16) * HD_ + 32 + quad * 8);
    };
    auto loadV = [&](int c, short8* vf) {
        const unsigned short* vc = vp + (size_t)c * VCS + quad * 8;
#pragma unroll
        for (int g2 = 0; g2 < 4; g2++)
            vf[g2] = *(const short8*)(vc + (g2 * 16 + l16) * 32);
    };
    auto readBias = [&](int c, float* bia) {
#pragma unroll
        for (int g = 0; g < 2; g++)
#pragma unroll
            for (int reg = 0; reg < 4; reg++) {
                int da = __sad(rpx[g][reg], c, 0u);
                bia[g * 4 + reg] = tabs[da * 33 + dbb[g][reg]];
            }
    };
    auto qk = [&](f32x4* s, const short8* kf) {
        s[0] = __builtin_amdgcn_mfma_f32_16x16x32_bf16(qf[0], kf[0], zero4, 0, 0, 0);
        s[0] = __builtin_amdgcn_mfma_f32_16x16x32_bf16(qf[1], kf[1], s[0], 0, 0, 0);
        s[1] = __builtin_amdgcn_mfma_f32_16x16x32_bf16(qf[0], kf[2], zero4, 0, 0, 0);
        s[1] = __builtin_amdgcn_mfma_f32_16x16x32_bf16(qf[1], kf[3], s[1], 0, 0, 0);
    };
    auto pv = [&](int buf, const short8* vf) {
        short8 pf = *(const short8*)&Pl[wave][buf][l16 * 40 + quad * 8];
#pragma unroll
        for (int g2 = 0; g2 < 4; g2++)
            o_acc[g2] = __builtin_amdgcn_mfma_f32_16x16x32_bf16(pf, vf[g2], o_acc[g2], 0, 0, 0);
        l_acc = __builtin_amdgcn_mfma_f32_16x16x32_bf16(pf, ones, l_acc, 0, 0, 0);
    };
    auto expWrite = [&](f32x4* s, const float* bia, int buf, bool first, bool last) {
        float p0[4], p1[4];
#pragma unroll
        for (int reg = 0; reg < 4; reg++) {
            float s0 = s[0][reg] + ((rz[reg] || (first && l16 == 0)) ? 0.f : bia[reg]);
            float s1 = s[1][reg] + (rz[reg] ? 0.f : bia[4 + reg]);
            if (last) {                       // only key 1024 (g0, l16==0) valid
                if (l16 != 0) s0 = -1e30f;
                s1 = -1e30f;
            }
            p0[reg] = __expf(s0);
            p1[reg] = __expf(s1);
        }
        unsigned short* plw = &Pl[wave][buf][0];
#pragma unroll
        for (int reg = 0; reg < 4; reg++) {
            plw[(quad * 4 + reg) * 40 + l16]      = bf16u(p0[reg]);
            plw[(quad * 4 + reg) * 40 + 16 + l16] = bf16u(p1[reg]);
        }
    };

    short8 kA[4], kB[4], vA[4], vB[4];
    // body with full pipeline: read P(prev) early, QK(c), prefetch K(c+2),
    // PV(c-1), bias+exp(c), loadV(c), write P(c).
    auto body = [&](int c, short8* kcur, const short8* vprev, short8* vcur,
                    int prevBuf, int curBuf, bool last) {
        float bia[8];
        readBias(c, bia);
        f32x4 s[2];
        qk(s, kcur);
        loadK(c + 2, kcur);
        pv(prevBuf, vprev);
        loadV(c, vcur);
        expWrite(s, bia, curBuf, false, last);
    };

    if (seg == 0) {
        // chunks 0..16
        loadK(0, kA); loadK(1, kB);
        {   // body 0: no PV yet
            float bia[8];
            readBias(0, bia);
            f32x4 s[2];
            qk(s, kA);
            loadK(2, kA);
            loadV(0, vA);
            expWrite(s, bia, 0, true, false);
        }
#pragma unroll 1
        for (int c = 1; c <= 15; c += 2) {
            body(c,     kB, vA, vB, 0, 1, false);
            body(c + 1, kA, vB, vA, 1, 0, false);
        }
        pv(0, vA);           // PV(16)
    } else {
        // chunks 17..32
        loadK(17, kA); loadK(18, kB);
        {   // body 17: no PV yet (writes buf 1 = 17&1)
            float bia[8];
            readBias(17, bia);
            f32x4 s[2];
            qk(s, kA);
            loadK(19, kA);
            loadV(17, vA);
            expWrite(s, bia, 1, false, false);
        }
#pragma unroll 1
        for (int c = 18; c <= 30; c += 2) {
            body(c,     kB, vA, vB, 1, 0, false);
            body(c + 1, kA, vB, vA, 0, 1, false);
        }
        body(32, kB, vA, vB, 1, 0, true);   // final partial chunk (masked)
        pv(0, vB);           // PV(32)
    }

    // store partials (C-layout rows), NO division here
#pragma unroll
    for (int reg = 0; reg < 4; reg++) {
        int r = r0c + reg;
        if (r < N_) {
            size_t rl = (size_t)bh * N_ + r;
            unsigned short* prow = po + (rl * 2 + seg) * 64;
#pragma unroll
            for (int g2 = 0; g2 < 4; g2++)
                prow[g2 * 16 + l16] = bf16u(o_acc[g2][reg]);
            if (l16 == 0) pl[rl * 2 + seg] = l_acc[reg];
        }
    }
}

// ---------------------------------------------------------------------------
// Combine: o = (po[seg0] + po[seg1]) / (pl[seg0] + pl[seg1]) -> ob bf16
// ---------------------------------------------------------------------------
__global__ __launch_bounds__(256) void attn_combine(
        const unsigned short* __restrict__ po, const float* __restrict__ pl,
        unsigned short* __restrict__ ob) {
    int tid = threadIdx.x;
    int row = blockIdx.x * 4 + (tid >> 6);
    int dim = tid & 63;
    size_t base = (size_t)row * 2 * 64;
    float o = bf16f(po[base + dim]) + bf16f(po[base + 64 + dim]);
    float l = pl[row * 2] + pl[row * 2 + 1];
    int b = row / (H_ * N_);
    int rem = row - b * (H_ * N_);
    int h = rem / N_;
    int r = rem - h * N_;
    ob[((size_t)b * N_ + r) * C_ + h * HD_ + dim] = bf16u(o / l);
}

// ---------------------------------------------------------------------------
extern "C" void kernel_launch(void* const* d_in, const int* in_sizes, int n_in,
                              void* d_out, int out_size, void* d_ws, size_t ws_size,
                              hipStream_t stream) {
    const float* x      = (const float*)d_in[0];
    const float* qkv_w  = (const float*)d_in[1];
    const float* proj_w = (const float*)d_in[2];
    const float* proj_b = (const float*)d_in[3];
    const float* wg_w   = (const float*)d_in[4];
    const float* wg_b   = (const float*)d_in[5];
    float* out = (float*)d_out;

    const size_t per = PER_;
    char* ws = (char*)d_ws;
    float* tab = (float*)ws;                                     // 32 KB

    // Region R: xb+wqkvb (live: prep -> gemm_qkv) overlapped with po+pl
    // (live: attn -> combine). Disjoint lifetimes within one replay.
    char* R = ws + (32 << 10);
    unsigned short* xb    = (unsigned short*)R;                  // 8,396,800 B
    unsigned short* wqkvb = (unsigned short*)(R + 8396800);      // 1,572,864 B
    unsigned short* po    = (unsigned short*)R;                  // 16,793,600 B
    float*          pl    = (float*)(R + 16793600);              //    524,800 B
    char* after = R + 17318400;
    unsigned short* wprjb = (unsigned short*)after;              // 524,288 B
    unsigned short* qb    = (unsigned short*)(after + 524288);
    unsigned short* kb    = qb + per;
    unsigned short* vtc   = kb + per;                            // [bh][ch][dim][32]
    unsigned short* ob    = vtc + (size_t)B_ * H_ * NCH * VCS;   // [B][N][C] bf16

    prep_kernel<<<32 + CAST_BLKS, 256, 0, stream>>>(x, qkv_w, proj_w, wg_w, wg_b,
                                                    xb, wqkvb, wprjb, tab);
    gemm_qkv_mfma<<<dim3(12, 65), 256, 0, stream>>>(xb, wqkvb, qb, kb, vtc);
    attn_mfma<<<17 * 64 * 2, 256, 0, stream>>>(qb, kb, vtc, tab, po, pl);
    attn_combine<<<NROWS / 4, 256, 0, stream>>>(po, pl, ob);
    gemm_proj_mfma<<<dim3(4, 65), 256, 0, stream>>>(ob, wprjb, proj_b, out);
}

// Round 10
// 245.735 us; speedup vs baseline: 1.5459x; 1.0741x over previous
//
#include <hip/hip_runtime.h>
#include <hip/hip_bf16.h>
#include <math.h>

#define B_  8
#define N_  1025
#define C_  512
#define H_  8
#define HD_ 64
#define M_  (B_ * N_)   // 8200
#define NCH 33          // ceil(N_/32) key chunks
#define VCS 2048        // shorts per vtc chunk: 64 dims * 32 keys
#define SP  1056        // P row stride (33 chunks * 32), bf16

typedef __attribute__((ext_vector_type(8))) short short8;
typedef __attribute__((ext_vector_type(4))) float f32x4;

__device__ inline unsigned short bf16u(float x) {
    __hip_bfloat16 t = __float2bfloat16(x);
    return *(unsigned short*)&t;
}
__device__ inline void load_lds16(const void* g, void* l) {
    __builtin_amdgcn_global_load_lds(
        (const __attribute__((address_space(1))) unsigned int*)g,
        (__attribute__((address_space(3))) unsigned int*)l, 16, 0, 0);
}

// ---------------------------------------------------------------------------
// Fused prep: blocks 0..31 build the H x 32 x 32 bias table (geometry bias
// collapses: dw=dh=0, depends only on |dpx|,|dpy|); remaining blocks cast
// x / qkv_w / proj_w fp32 -> bf16.
// ---------------------------------------------------------------------------
#define PER_ ((size_t)B_ * H_ * N_ * HD_)      // 4,198,400
#define SZ_QKVW (3 * C_ * C_)
#define SZ_PRJW (C_ * C_)
#define CAST_BLKS ((4198400 + 786432 + 262144) / 4 / 256)   // 5124

__global__ void prep_kernel(const float* __restrict__ x,
                            const float* __restrict__ qkv_w,
                            const float* __restrict__ proj_w,
                            const float* __restrict__ wg_w,
                            const float* __restrict__ wg_b,
                            unsigned short* __restrict__ xb,
                            unsigned short* __restrict__ wqkvb,
                            unsigned short* __restrict__ wprjb,
                            float* __restrict__ tab) {
    int blk = blockIdx.x;
    int tid = threadIdx.x;
    if (blk < 32) {
        int idx = blk * 256 + tid;
        int h = idx >> 10;
        int a = (idx >> 5) & 31;
        int b = idx & 31;
        float dx = logf(fmaxf((float)a * (1.0f / 33.0f), 0.001f));
        float dy = logf(fmaxf((float)b * (1.0f / 33.0f), 0.001f));
        const float* w = wg_w + h * 64;
        float acc = wg_b[h];
#pragma unroll
        for (int k = 0; k < 8; k++) {
            float f = powf(1000.0f, -(float)k * 0.125f);
            float X = 100.0f * dx * f;
            float Y = 100.0f * dy * f;
            acc += w[k]      * sinf(X);
            acc += w[8 + k]  * sinf(Y);
            acc += w[32 + k] * cosf(X);
            acc += w[40 + k] * cosf(Y);
            acc += w[48 + k] + w[56 + k];
        }
        tab[idx] = logf(fmaxf(fmaxf(acc, 0.0f), 1e-6f));
        return;
    }
    long i4 = ((long)(blk - 32) * 256 + tid) * 4;
    const float* src;
    unsigned short* dst;
    long off;
    if (i4 < (long)PER_)                    { src = x;      dst = xb;    off = i4; }
    else if (i4 < (long)PER_ + SZ_QKVW)     { src = qkv_w;  dst = wqkvb; off = i4 - PER_; }
    else                                    { src = proj_w; dst = wprjb; off = i4 - PER_ - SZ_QKVW; }
    float4 v = *(const float4*)(src + off);
    ushort4 p;
    p.x = bf16u(v.x); p.y = bf16u(v.y); p.z = bf16u(v.z); p.w = bf16u(v.w);
    *(ushort4*)(dst + off) = p;
}

// ---------------------------------------------------------------------------
// MFMA GEMM, 128x128 tile, BK=32, 4 waves. q/k blocks use swapped-operand
// MFMA -> ushort4 stores; v scatters to chunked vtc [bh][ch][dim][32].
// ---------------------------------------------------------------------------
#define GK 512

__global__ __launch_bounds__(256) void gemm_qkv_mfma(
        const unsigned short* __restrict__ A, const unsigned short* __restrict__ W,
        unsigned short* __restrict__ qb, unsigned short* __restrict__ kb,
        unsigned short* __restrict__ vtc) {
    __shared__ __align__(16) unsigned short As[128 * 32];
    __shared__ __align__(16) unsigned short Bs[128 * 32];
    int tid = threadIdx.x;
    int w = tid >> 6, lane = tid & 63;
    int quad = lane >> 4, l16 = lane & 15;
    int m0 = blockIdx.y * 128;
    int n0 = blockIdx.x * 128;
    int wr = (w >> 1) * 64, wc = (w & 1) * 64;

    int c0 = tid, c1 = tid + 256;
    int a_r0 = min(m0 + (c0 >> 2), M_ - 1), a_c0 = (c0 & 3) * 8;
    int a_r1 = min(m0 + (c1 >> 2), M_ - 1), a_c1 = (c1 & 3) * 8;
    int b_r0 = n0 + (c0 >> 2), b_r1 = n0 + (c1 >> 2);

    int which = n0 >> 9;                       // 0=q 1=k 2=v
    int h = ((n0 + wc) >> 6) & 7;

    f32x4 acc[4][4];
    const f32x4 zero4 = {0.f, 0.f, 0.f, 0.f};
#pragma unroll
    for (int mi = 0; mi < 4; mi++)
#pragma unroll
        for (int ni = 0; ni < 4; ni++) acc[mi][ni] = zero4;

    if (which < 2) {
        for (int k0 = 0; k0 < GK; k0 += 32) {
            __syncthreads();
            load_lds16(A + (size_t)a_r0 * GK + k0 + a_c0, &As[w * 512]);
            load_lds16(A + (size_t)a_r1 * GK + k0 + a_c1, &As[2048 + w * 512]);
            load_lds16(W + (size_t)b_r0 * GK + k0 + a_c0, &Bs[w * 512]);
            load_lds16(W + (size_t)b_r1 * GK + k0 + a_c1, &Bs[2048 + w * 512]);
            __syncthreads();
            short8 af[4], bf[4];
#pragma unroll
            for (int mi = 0; mi < 4; mi++)
                af[mi] = *(const short8*)&As[(wr + mi * 16 + l16) * 32 + quad * 8];
#pragma unroll
            for (int ni = 0; ni < 4; ni++)
                bf[ni] = *(const short8*)&Bs[(wc + ni * 16 + l16) * 32 + quad * 8];
#pragma unroll
            for (int mi = 0; mi < 4; mi++)
#pragma unroll
                for (int ni = 0; ni < 4; ni++)
                    acc[mi][ni] = __builtin_amdgcn_mfma_f32_16x16x32_bf16(
                        bf[ni], af[mi], acc[mi][ni], 0, 0, 0);
        }
        unsigned short* dst = (which == 0) ? qb : kb;
        float sc = (which == 0) ? 0.125f : 1.0f;
#pragma unroll
        for (int mi = 0; mi < 4; mi++) {
            int m = m0 + wr + mi * 16 + l16;
            if (m < M_) {
                int bb = m / N_;
                int i  = m - bb * N_;
                unsigned short* row = dst + ((size_t)(bb * H_ + h) * N_ + i) * HD_;
#pragma unroll
                for (int ni = 0; ni < 4; ni++) {
                    ushort4 pk;
                    pk.x = bf16u(acc[mi][ni][0] * sc);
                    pk.y = bf16u(acc[mi][ni][1] * sc);
                    pk.z = bf16u(acc[mi][ni][2] * sc);
                    pk.w = bf16u(acc[mi][ni][3] * sc);
                    *(ushort4*)(row + ni * 16 + quad * 4) = pk;
                }
            }
        }
    } else {
        for (int k0 = 0; k0 < GK; k0 += 32) {
            __syncthreads();
            load_lds16(A + (size_t)a_r0 * GK + k0 + a_c0, &As[w * 512]);
            load_lds16(A + (size_t)a_r1 * GK + k0 + a_c1, &As[2048 + w * 512]);
            load_lds16(W + (size_t)b_r0 * GK + k0 + a_c0, &Bs[w * 512]);
            load_lds16(W + (size_t)b_r1 * GK + k0 + a_c1, &Bs[2048 + w * 512]);
            __syncthreads();
            short8 af[4], bf[4];
#pragma unroll
            for (int mi = 0; mi < 4; mi++)
                af[mi] = *(const short8*)&As[(wr + mi * 16 + l16) * 32 + quad * 8];
#pragma unroll
            for (int ni = 0; ni < 4; ni++)
                bf[ni] = *(const short8*)&Bs[(wc + ni * 16 + l16) * 32 + quad * 8];
#pragma unroll
            for (int mi = 0; mi < 4; mi++)
#pragma unroll
                for (int ni = 0; ni < 4; ni++)
                    acc[mi][ni] = __builtin_amdgcn_mfma_f32_16x16x32_bf16(
                        af[mi], bf[ni], acc[mi][ni], 0, 0, 0);
        }
#pragma unroll
        for (int mi = 0; mi < 4; mi++)
#pragma unroll
            for (int reg = 0; reg < 4; reg++) {
                int m = m0 + wr + mi * 16 + quad * 4 + reg;
                if (m < M_) {
                    int bb = m / N_;
                    int i  = m - bb * N_;
                    int ch = i >> 5, key = i & 31;
                    size_t base = ((size_t)(bb * H_ + h) * NCH + ch) * VCS + key;
#pragma unroll
                    for (int ni = 0; ni < 4; ni++)
                        vtc[base + (size_t)(ni * 16 + l16) * 32] = bf16u(acc[mi][ni][reg]);
                }
            }
    }
}

__global__ __launch_bounds__(256) void gemm_proj_mfma(
        const unsigned short* __restrict__ A, const unsigned short* __restrict__ W,
        const float* __restrict__ bias, float* __restrict__ out) {
    __shared__ __align__(16) unsigned short As[128 * 32];
    __shared__ __align__(16) unsigned short Bs[128 * 32];
    int tid = threadIdx.x;
    int w = tid >> 6, lane = tid & 63;
    int quad = lane >> 4, l16 = lane & 15;
    int m0 = blockIdx.y * 128;
    int n0 = blockIdx.x * 128;
    int wr = (w >> 1) * 64, wc = (w & 1) * 64;

    int c0 = tid, c1 = tid + 256;
    int a_r0 = min(m0 + (c0 >> 2), M_ - 1), a_c0 = (c0 & 3) * 8;
    int a_r1 = min(m0 + (c1 >> 2), M_ - 1), a_c1 = (c1 & 3) * 8;
    int b_r0 = n0 + (c0 >> 2), b_r1 = n0 + (c1 >> 2);

    f32x4 acc[4][4];
    const f32x4 zero4 = {0.f, 0.f, 0.f, 0.f};
#pragma unroll
    for (int mi = 0; mi < 4; mi++)
#pragma unroll
        for (int ni = 0; ni < 4; ni++) acc[mi][ni] = zero4;

    for (int k0 = 0; k0 < GK; k0 += 32) {
        __syncthreads();
        load_lds16(A + (size_t)a_r0 * GK + k0 + a_c0, &As[w * 512]);
        load_lds16(A + (size_t)a_r1 * GK + k0 + a_c1, &As[2048 + w * 512]);
        load_lds16(W + (size_t)b_r0 * GK + k0 + a_c0, &Bs[w * 512]);
        load_lds16(W + (size_t)b_r1 * GK + k0 + a_c1, &Bs[2048 + w * 512]);
        __syncthreads();
        short8 af[4], bf[4];
#pragma unroll
        for (int mi = 0; mi < 4; mi++)
            af[mi] = *(const short8*)&As[(wr + mi * 16 + l16) * 32 + quad * 8];
#pragma unroll
        for (int ni = 0; ni < 4; ni++)
            bf[ni] = *(const short8*)&Bs[(wc + ni * 16 + l16) * 32 + quad * 8];
#pragma unroll
        for (int mi = 0; mi < 4; mi++)
#pragma unroll
            for (int ni = 0; ni < 4; ni++)
                acc[mi][ni] = __builtin_amdgcn_mfma_f32_16x16x32_bf16(
                    af[mi], bf[ni], acc[mi][ni], 0, 0, 0);
    }

    float bvals[4];
#pragma unroll
    for (int ni = 0; ni < 4; ni++) bvals[ni] = bias[n0 + wc + ni * 16 + l16];
#pragma unroll
    for (int mi = 0; mi < 4; mi++)
#pragma unroll
        for (int reg = 0; reg < 4; reg++) {
            int m = m0 + wr + mi * 16 + quad * 4 + reg;
            if (m < M_) {
                float* row = out + (size_t)m * C_ + n0 + wc;
#pragma unroll
                for (int ni = 0; ni < 4; ni++)
                    row[ni * 16 + l16] = acc[mi][ni][reg] + bvals[ni];
            }
        }
}

// ---------------------------------------------------------------------------
// Attention pass 1: P = exp(Q K^T + bias), bf16, [bh][row][SP].
// Fixed-max softmax (m==0) -> no row reduction needed; pure GEMM + epilogue.
// grid = 5184 (8 xcd x 8 bhi x 81 tiles), 256 thr. 128x128 tile, K=64.
// Swapped-operand MFMA: lane holds 4 consecutive key-cols -> ushort4 stores.
// ---------------------------------------------------------------------------
__global__ __launch_bounds__(256) void attn_qk_exp(
        const unsigned short* __restrict__ qg,
        const unsigned short* __restrict__ kg,
        const float* __restrict__ tab,
        unsigned short* __restrict__ P) {
    __shared__ __align__(16) unsigned short Qs[128 * 64];  // 16 KB
    __shared__ __align__(16) unsigned short Ks[128 * 64];  // 16 KB
    __shared__ float tabs[34 * 33];                        // 4.5 KB

    int tid = threadIdx.x;
    int w = tid >> 6, lane = tid & 63;
    int quad = lane >> 4, l16 = lane & 15;

    int lin = blockIdx.x;
    int xcd = lin & 7;
    int rest = lin >> 3;
    int bhi = rest & 7;
    int t = rest >> 3;               // 0..80
    int mt = t / 9, nt = t - mt * 9;
    int bh = xcd * 8 + bhi;
    int h = bh & 7;

    const unsigned short* qp = qg + (size_t)bh * N_ * HD_;
    const unsigned short* kp = kg + (size_t)bh * N_ * HD_;

    for (int i = tid; i < 1024; i += 256)
        tabs[(i >> 5) * 33 + (i & 31)] = tab[h * 1024 + i];

    // stage Q[mt], K[nt]: 1024 16B-chunks each (4 rounds of 256)
#pragma unroll
    for (int r = 0; r < 4; r++) {
        int ch = r * 256 + tid;
        int row = ch >> 3, col8 = (ch & 7) * 8;
        int qr = min(mt * 128 + row, N_ - 1);
        int kr = min(nt * 128 + row, N_ - 1);
        load_lds16(qp + (size_t)qr * HD_ + col8, &Qs[r * 2048 + w * 512]);
        load_lds16(kp + (size_t)kr * HD_ + col8, &Ks[r * 2048 + w * 512]);
    }
    __syncthreads();

    int wr = (w >> 1) * 64, wc = (w & 1) * 64;
    f32x4 acc[4][4];
    const f32x4 zero4 = {0.f, 0.f, 0.f, 0.f};
#pragma unroll
    for (int mi = 0; mi < 4; mi++)
#pragma unroll
        for (int ni = 0; ni < 4; ni++) acc[mi][ni] = zero4;

#pragma unroll
    for (int ks = 0; ks < 2; ks++) {
        short8 af[4], bf[4];
#pragma unroll
        for (int mi = 0; mi < 4; mi++)
            af[mi] = *(const short8*)&Qs[(wr + mi * 16 + l16) * 64 + ks * 32 + quad * 8];
#pragma unroll
        for (int ni = 0; ni < 4; ni++)
            bf[ni] = *(const short8*)&Ks[(wc + ni * 16 + l16) * 64 + ks * 32 + quad * 8];
#pragma unroll
        for (int mi = 0; mi < 4; mi++)
#pragma unroll
            for (int ni = 0; ni < 4; ni++)
                acc[mi][ni] = __builtin_amdgcn_mfma_f32_16x16x32_bf16(
                    bf[ni], af[mi], acc[mi][ni], 0, 0, 0);
    }

    // epilogue: per (ni,reg) key-col constants (mi-independent)
    int jx[4][4], jy[4][4];
    bool jo[4][4], jz[4][4];
#pragma unroll
    for (int ni = 0; ni < 4; ni++)
#pragma unroll
        for (int reg = 0; reg < 4; reg++) {
            int jn = nt * 128 + wc + ni * 16 + quad * 4 + reg;
            int ji = jn - 1;
            jx[ni][reg] = ji >> 5;
            jy[ni][reg] = ji & 31;
            jo[ni][reg] = (jn >= N_);
            jz[ni][reg] = (jn == 0);
        }

    unsigned short* Pb = P + (size_t)bh * N_ * SP;
#pragma unroll
    for (int mi = 0; mi < 4; mi++) {
        int rowm = mt * 128 + wr + mi * 16 + l16;
        if (rowm >= N_) continue;
        int riv = rowm - 1;
        int rpx = riv >> 5, rpy = riv & 31;
        bool mz = (rowm == 0);
        unsigned short* prow = Pb + (size_t)rowm * SP;
#pragma unroll
        for (int ni = 0; ni < 4; ni++) {
            int coln = nt * 128 + wc + ni * 16 + quad * 4;
            if (coln >= SP) continue;
            ushort4 pk;
            float pv[4];
#pragma unroll
            for (int reg = 0; reg < 4; reg++) {
                if (jo[ni][reg]) { pv[reg] = 0.f; continue; }
                float bia = 0.f;
                if (!mz && !jz[ni][reg]) {
                    int da = __sad(rpx, jx[ni][reg], 0u);
                    int db = __sad(rpy, jy[ni][reg], 0u);
                    bia = tabs[da * 33 + db];
                }
                pv[reg] = __expf(acc[mi][ni][reg] + bia);
            }
            pk.x = bf16u(pv[0]); pk.y = bf16u(pv[1]);
            pk.z = bf16u(pv[2]); pk.w = bf16u(pv[3]);
            *(ushort4*)(prow + coln) = pk;
        }
    }
}

// ---------------------------------------------------------------------------
// Attention pass 2: O = P @ V, l = P @ ones (exact, fixed-max), o = O/l -> ob.
// grid = 1088 (8 xcd x 8 bhi x 17 mtiles of 64 rows), 256 thr, no LDS/barriers.
// Streaming K=1056 with depth-2 register double-buffering.
// ---------------------------------------------------------------------------
__global__ __launch_bounds__(256) void attn_pv(
        const unsigned short* __restrict__ P,
        const unsigned short* __restrict__ vtc,
        unsigned short* __restrict__ ob) {
    int tid = threadIdx.x;
    int w = tid >> 6, lane = tid & 63;
    int quad = lane >> 4, l16 = lane & 15;

    int lin = blockIdx.x;
    int xcd = lin & 7;
    int rest = lin >> 3;
    int bhi = rest & 7;
    int mt = rest >> 3;              // 0..16
    int bh = xcd * 8 + bhi;
    int b = bh >> 3, h = bh & 7;

    const unsigned short* Pb = P + (size_t)bh * N_ * SP;
    const unsigned short* vp = vtc + (size_t)bh * NCH * VCS;

    int row0 = mt * 64 + w * 16;
    int rowA = min(row0 + l16, N_ - 1);
    const unsigned short* prow = Pb + (size_t)rowA * SP + quad * 8;

    f32x4 o_acc[4], l_acc;
    const f32x4 zero4 = {0.f, 0.f, 0.f, 0.f};
#pragma unroll
    for (int g2 = 0; g2 < 4; g2++) o_acc[g2] = zero4;
    l_acc = zero4;
    short8 ones;
    {
        short one_bf = (short)0x3F80;
#pragma unroll
        for (int j = 0; j < 8; j++) ones[j] = one_bf;
    }

    auto loadP = [&](int c, short8& pf) {
        pf = *(const short8*)(prow + c * 32);
    };
    auto loadVf = [&](int c, short8* vf) {
        const unsigned short* vc = vp + (size_t)c * VCS + quad * 8;
#pragma unroll
        for (int g2 = 0; g2 < 4; g2++)
            vf[g2] = *(const short8*)(vc + (g2 * 16 + l16) * 32);
    };
    auto compute = [&](const short8& pf, const short8* vf) {
#pragma unroll
        for (int g2 = 0; g2 < 4; g2++)
            o_acc[g2] = __builtin_amdgcn_mfma_f32_16x16x32_bf16(pf, vf[g2], o_acc[g2], 0, 0, 0);
        l_acc = __builtin_amdgcn_mfma_f32_16x16x32_bf16(pf, ones, l_acc, 0, 0, 0);
    };

    short8 pA, pB, vA[4], vB[4];
    loadP(0, pA); loadVf(0, vA);
    loadP(1, pB); loadVf(1, vB);
#pragma unroll 1
    for (int c = 0; c <= 30; c += 2) {
        compute(pA, vA);
        if (c + 2 <= 32) { loadP(c + 2, pA); loadVf(c + 2, vA); }
        compute(pB, vB);
        if (c + 3 <= 32) { loadP(c + 3, pB); loadVf(c + 3, vB); }
    }
    compute(pA, vA);     // chunk 32

    // epilogue: o/l, bf16 store (C-layout rows = quad*4+reg)
#pragma unroll
    for (int reg = 0; reg < 4; reg++) {
        int r = row0 + quad * 4 + reg;
        if (r < N_) {
            float inv = 1.0f / l_acc[reg];
            unsigned short* orow = ob + ((size_t)b * N_ + r) * C_ + h * HD_ + l16;
#pragma unroll
            for (int g2 = 0; g2 < 4; g2++)
                orow[g2 * 16] = bf16u(o_acc[g2][reg] * inv);
        }
    }
}

// ---------------------------------------------------------------------------
extern "C" void kernel_launch(void* const* d_in, const int* in_sizes, int n_in,
                              void* d_out, int out_size, void* d_ws, size_t ws_size,
                              hipStream_t stream) {
    const float* x      = (const float*)d_in[0];
    const float* qkv_w  = (const float*)d_in[1];
    const float* proj_w = (const float*)d_in[2];
    const float* proj_b = (const float*)d_in[3];
    const float* wg_w   = (const float*)d_in[4];
    const float* wg_b   = (const float*)d_in[5];
    float* out = (float*)d_out;

    const size_t per = PER_;
    char* ws = (char*)d_ws;
    float* tab            = (float*)ws;                           // 32 KB
    unsigned short* xb    = (unsigned short*)(ws + (32 << 10));   // 8,396,800 B
    unsigned short* wqkvb = xb + per;                             // 1,572,864 B
    unsigned short* wprjb = wqkvb + (size_t)SZ_QKVW;              //   524,288 B
    unsigned short* qb    = wprjb + (size_t)SZ_PRJW;              // 8,396,800 B
    unsigned short* kb    = qb + per;                             // 8,396,800 B
    unsigned short* vtc   = kb + per;                             // 8,650,752 B
    unsigned short* ob    = vtc + (size_t)64 * NCH * VCS;         // 8,396,800 B
    unsigned short* P     = ob + per;                             // 138,547,200 B

    prep_kernel<<<32 + CAST_BLKS, 256, 0, stream>>>(x, qkv_w, proj_w, wg_w, wg_b,
                                                    xb, wqkvb, wprjb, tab);
    gemm_qkv_mfma<<<dim3(12, 65), 256, 0, stream>>>(xb, wqkvb, qb, kb, vtc);
    attn_qk_exp<<<8 * 8 * 81, 256, 0, stream>>>(qb, kb, tab, P);
    attn_pv<<<8 * 8 * 17, 256, 0, stream>>>(P, vtc, ob);
    gemm_proj_mfma<<<dim3(4, 65), 256, 0, stream>>>(ob, wprjb, proj_b, out);
}